// Round 1
// baseline (15.826 us; speedup 1.0000x reference)
//
#include <hip/hip_runtime.h>

// QuantumLayer via bond-dim-2 transfer-matrix contraction.
//
// Circuit: |0>^8 -> RY(x_i) -> RY(w0_i) -> CNOT chain -> RY(w1_i) -> CNOT chain -> <Z_i>.
// Fold RY(x)·RY(w0) = RY(alpha), alpha_i = x_i + w0_i  (same-axis rotations add).
// Psi = C|prod state>:  Psi(m) = phi_0(m_0) * prod_w phi_w(m_w ^ m_{w-1}),
//   phi_w = (a_w, b_w) = (cos(alpha_w/2), sin(alpha_w/2)).
// Final chain pulled into measurement: C^dag Z_i C = Z_0...Z_i (prefix parity).
// RY(w1) layer conjugates: Z_w -> cos(b1_w) Z - sin(b1_w) X  =: O_w.
// z_i = <Psi| (⊗_{w<=i} O_w) |Psi>  contracted left-to-right with the symmetric
// 2x2 environment f[(m,m')] (f01 == f10 =: u), per-site update:
//   h00 = a^2 f00 + b^2 f11 + 2ab u
//   h11 = b^2 f00 + a^2 f11 + 2ab u
//   h01 = ab (f00 + f11) + u            (uses a^2+b^2 = 1)
//   f00 =  c h00 ; f11 = -c h11 ; u = -s h01      (c = cos w1_w, s = sin w1_w)
// Close at site i: tail contraction of sites >i telescopes to 1 on the diagonal
// and sin(alpha_{i+1}) off-diagonal:
//   z_i = f00 + f11 + sin(alpha_{i+1}) * 2u      (i=7: tail factor = 1)

__global__ __launch_bounds__(256) void qlayer_mps_kernel(
    const float* __restrict__ x,   // (B, 8)
    const float* __restrict__ w,   // (2, 8) flat: w0[0..7], w1[0..7]
    float* __restrict__ out,       // (B, 8)
    int B)
{
    int b = blockIdx.x * blockDim.x + threadIdx.x;
    if (b >= B) return;

    // coalesced 2x float4 load of this sample's angles
    const float4* x4 = reinterpret_cast<const float4*>(x) + (size_t)b * 2;
    float4 xlo = x4[0];
    float4 xhi = x4[1];
    float xv[8] = {xlo.x, xlo.y, xlo.z, xlo.w, xhi.x, xhi.y, xhi.z, xhi.w};

    float a[8];   // cos(alpha/2)
    float bs[8];  // sin(alpha/2)
    float sa[8];  // sin(alpha) = 2ab
    float cb[8];  // cos(w1)
    float sb[8];  // sin(w1)
#pragma unroll
    for (int i = 0; i < 8; ++i) {
        float half = 0.5f * (xv[i] + w[i]);      // (x_i + w0_i)/2
        __sincosf(half, &bs[i], &a[i]);
        sa[i] = 2.0f * a[i] * bs[i];
        __sincosf(w[8 + i], &sb[i], &cb[i]);     // full angle for O_w
    }

    // site 0 init: f[(p,p')] = phi0(p) phi0(p') O_0(p',p),  O = [[c,-s],[-s,-c]]
    float f00 = a[0] * a[0] * cb[0];
    float f11 = -(bs[0] * bs[0]) * cb[0];
    float u   = -(a[0] * bs[0]) * sb[0];

    float z[8];
#pragma unroll
    for (int i = 0; i < 8; ++i) {
        if (i > 0) {
            float aa  = a[i] * a[i];
            float bb  = bs[i] * bs[i];
            float ab2 = sa[i];                    // 2ab
            float h00 = aa * f00 + bb * f11 + ab2 * u;
            float h11 = bb * f00 + aa * f11 + ab2 * u;
            float h01 = 0.5f * ab2 * (f00 + f11) + u;
            f00 = cb[i] * h00;
            f11 = -cb[i] * h11;
            u   = -sb[i] * h01;
        }
        float tail = (i < 7) ? sa[i + 1] : 1.0f;
        z[i] = (f00 + f11) + tail * (u + u);
    }

    float4* o4 = reinterpret_cast<float4*>(out) + (size_t)b * 2;
    o4[0] = make_float4(z[0], z[1], z[2], z[3]);
    o4[1] = make_float4(z[4], z[5], z[6], z[7]);
}

extern "C" void kernel_launch(void* const* d_in, const int* in_sizes, int n_in,
                              void* d_out, int out_size, void* d_ws, size_t ws_size,
                              hipStream_t stream) {
    const float* x = (const float*)d_in[0];
    const float* w = (const float*)d_in[1];
    float* out = (float*)d_out;
    int B = in_sizes[0] / 8;
    int threads = 256;
    int blocks = (B + threads - 1) / threads;
    hipLaunchKernelGGL(qlayer_mps_kernel, dim3(blocks), dim3(threads), 0, stream,
                       x, w, out, B);
}

// Round 2
// 11.453 us; speedup vs baseline: 1.3818x; 1.3818x over previous
//
#include <hip/hip_runtime.h>

// QuantumLayer via bond-dim-2 transfer-matrix contraction (full-angle form).
//
// Circuit: |0>^8 -> RY(x_i) -> RY(w0_i) -> CNOT chain -> RY(w1_i) -> CNOT chain -> <Z_i>.
// alpha_i = x_i + w0_i (same-axis RY fuse). With ca=cos(alpha), sa=sin(alpha):
//   a^2 = (1+ca)/2, b^2 = (1-ca)/2, 2ab = sa   (a=cos(alpha/2), b=sin(alpha/2))
// Environment f (symmetric 2x2: f00, f11, u), per-site update (site i>0):
//   S = (f00+f11)/2, D = (f00-f11)/2
//   h00 = S + ca*D + sa*u
//   h11 = S - ca*D + sa*u
//   h01 = sa*S + u
//   f00 = cb*h00 ; f11 = -cb*h11 ; u = -sb*h01     (cb=cos w1_i, sb=sin w1_i)
// Site 0 init: f00 = (1+ca)/2*cb, f11 = -(1-ca)/2*cb, u = -sa/2*sb.
// Close at site i: z_i = f00 + f11 + tail*2u, tail = sin(alpha_{i+1}) (1 for i=7).
// Validated algebra == round-0 kernel (passed, absmax 3.9e-3).

__global__ __launch_bounds__(256) void qlayer_mps_kernel(
    const float* __restrict__ x,   // (B, 8)
    const float* __restrict__ w,   // (2, 8) flat: w0[0..7], w1[0..7]
    float* __restrict__ out,       // (B, 8)
    int B)
{
    int b = blockIdx.x * blockDim.x + threadIdx.x;
    if (b >= B) return;

    // uniform weights: float4 loads -> scalar (s_load) candidates
    const float4* w4 = reinterpret_cast<const float4*>(w);
    float4 w0lo = w4[0], w0hi = w4[1];   // w0[0..7]
    float4 w1lo = w4[2], w1hi = w4[3];   // w1[0..7]
    float w0v[8] = {w0lo.x, w0lo.y, w0lo.z, w0lo.w, w0hi.x, w0hi.y, w0hi.z, w0hi.w};
    float w1v[8] = {w1lo.x, w1lo.y, w1lo.z, w1lo.w, w1hi.x, w1hi.y, w1hi.z, w1hi.w};

    // coalesced 2x float4 load of this sample's angles
    const float4* x4 = reinterpret_cast<const float4*>(x) + (size_t)b * 2;
    float4 xlo = x4[0];
    float4 xhi = x4[1];
    float xv[8] = {xlo.x, xlo.y, xlo.z, xlo.w, xhi.x, xhi.y, xhi.z, xhi.w};

    float ca[8], sa[8], cb[8], sb[8];
#pragma unroll
    for (int i = 0; i < 8; ++i) {
        __sincosf(xv[i] + w0v[i], &sa[i], &ca[i]);  // full angle alpha_i
        __sincosf(w1v[i], &sb[i], &cb[i]);          // full angle w1_i
    }

    // site 0
    float f00 = 0.5f * (1.0f + ca[0]) * cb[0];
    float f11 = -0.5f * (1.0f - ca[0]) * cb[0];
    float u   = -0.5f * sa[0] * sb[0];

    float z[8];
#pragma unroll
    for (int i = 0; i < 8; ++i) {
        if (i > 0) {
            float S = 0.5f * (f00 + f11);
            float D = 0.5f * (f00 - f11);
            float cD = ca[i] * D;
            float su = sa[i] * u;
            float h00 = (S + cD) + su;
            float h11 = (S - cD) + su;
            float h01 = fmaf(sa[i], S, u);
            f00 = cb[i] * h00;
            f11 = -cb[i] * h11;
            u   = -sb[i] * h01;
        }
        float tail = (i < 7) ? sa[i + 1] : 1.0f;
        z[i] = (f00 + f11) + tail * (u + u);
    }

    float4* o4 = reinterpret_cast<float4*>(out) + (size_t)b * 2;
    o4[0] = make_float4(z[0], z[1], z[2], z[3]);
    o4[1] = make_float4(z[4], z[5], z[6], z[7]);
}

extern "C" void kernel_launch(void* const* d_in, const int* in_sizes, int n_in,
                              void* d_out, int out_size, void* d_ws, size_t ws_size,
                              hipStream_t stream) {
    const float* x = (const float*)d_in[0];
    const float* w = (const float*)d_in[1];
    float* out = (float*)d_out;
    int B = in_sizes[0] / 8;
    int threads = 256;
    int blocks = (B + threads - 1) / threads;
    hipLaunchKernelGGL(qlayer_mps_kernel, dim3(blocks), dim3(threads), 0, stream,
                       x, w, out, B);
}

// Round 3
// 9.757 us; speedup vs baseline: 1.6220x; 1.1739x over previous
//
#include <hip/hip_runtime.h>

// QuantumLayer via bond-dim-2 transfer-matrix contraction (full-angle form),
// 2 samples per thread to amortize thread-uniform weight trig.
//
// Math (validated in R0/R1, passed absmax 3.9e-3):
// alpha_i = x_i + w0_i; ca=cos(alpha), sa=sin(alpha); cb=cos(w1), sb=sin(w1).
// Environment f (symmetric 2x2: f00, f11, u), site 0:
//   f00 = (1+ca)/2*cb, f11 = -(1-ca)/2*cb, u = -sa/2*sb
// site i>0:
//   S=(f00+f11)/2, D=(f00-f11)/2
//   f00 = cb*(S + ca*D + sa*u); f11 = -cb*(S - ca*D + sa*u); u = -sb*(sa*S + u)
// close: z_i = f00 + f11 + tail*2u, tail = sa[i+1] (1 for i=7).

__device__ __forceinline__ void contract_sample(
    const float xv[8], const float w0v[8],
    const float cb[8], const float sb[8],
    float z[8])
{
    float ca[8], sa[8];
#pragma unroll
    for (int i = 0; i < 8; ++i)
        __sincosf(xv[i] + w0v[i], &sa[i], &ca[i]);

    float f00 = 0.5f * (1.0f + ca[0]) * cb[0];
    float f11 = -0.5f * (1.0f - ca[0]) * cb[0];
    float u   = -0.5f * sa[0] * sb[0];

#pragma unroll
    for (int i = 0; i < 8; ++i) {
        if (i > 0) {
            float S = 0.5f * (f00 + f11);
            float D = 0.5f * (f00 - f11);
            float cD = ca[i] * D;
            float su = sa[i] * u;
            float h00 = (S + cD) + su;
            float h11 = (S - cD) + su;
            float h01 = fmaf(sa[i], S, u);
            f00 = cb[i] * h00;
            f11 = -cb[i] * h11;
            u   = -sb[i] * h01;
        }
        float tail = (i < 7) ? sa[i + 1] : 1.0f;
        z[i] = (f00 + f11) + tail * (u + u);
    }
}

__global__ __launch_bounds__(256) void qlayer_mps_kernel(
    const float* __restrict__ x,   // (B, 8)
    const float* __restrict__ w,   // (2, 8) flat: w0[0..7], w1[0..7]
    float* __restrict__ out,       // (B, 8)
    int half)                      // B/2
{
    int t = blockIdx.x * blockDim.x + threadIdx.x;
    if (t >= half) return;

    // uniform weights -> s_load; uniform trig computed once, shared by 2 samples
    const float4* w4 = reinterpret_cast<const float4*>(w);
    float4 w0lo = w4[0], w0hi = w4[1];
    float4 w1lo = w4[2], w1hi = w4[3];
    float w0v[8] = {w0lo.x, w0lo.y, w0lo.z, w0lo.w, w0hi.x, w0hi.y, w0hi.z, w0hi.w};
    float w1v[8] = {w1lo.x, w1lo.y, w1lo.z, w1lo.w, w1hi.x, w1hi.y, w1hi.z, w1hi.w};
    float cb[8], sb[8];
#pragma unroll
    for (int i = 0; i < 8; ++i)
        __sincosf(w1v[i], &sb[i], &cb[i]);

    // two samples: t and t+half, each a coalesced 2x float4 stream
    const float4* xa4 = reinterpret_cast<const float4*>(x) + (size_t)t * 2;
    const float4* xb4 = xa4 + (size_t)half * 2;
    float4 a0 = xa4[0], a1 = xa4[1];
    float4 b0 = xb4[0], b1 = xb4[1];
    float xa[8] = {a0.x, a0.y, a0.z, a0.w, a1.x, a1.y, a1.z, a1.w};
    float xb[8] = {b0.x, b0.y, b0.z, b0.w, b1.x, b1.y, b1.z, b1.w};

    float za[8], zb[8];
    contract_sample(xa, w0v, cb, sb, za);
    contract_sample(xb, w0v, cb, sb, zb);

    float4* oa4 = reinterpret_cast<float4*>(out) + (size_t)t * 2;
    float4* ob4 = oa4 + (size_t)half * 2;
    oa4[0] = make_float4(za[0], za[1], za[2], za[3]);
    oa4[1] = make_float4(za[4], za[5], za[6], za[7]);
    ob4[0] = make_float4(zb[0], zb[1], zb[2], zb[3]);
    ob4[1] = make_float4(zb[4], zb[5], zb[6], zb[7]);
}

extern "C" void kernel_launch(void* const* d_in, const int* in_sizes, int n_in,
                              void* d_out, int out_size, void* d_ws, size_t ws_size,
                              hipStream_t stream) {
    const float* x = (const float*)d_in[0];
    const float* w = (const float*)d_in[1];
    float* out = (float*)d_out;
    int B = in_sizes[0] / 8;
    int half = B / 2;
    int threads = 256;
    int blocks = (half + threads - 1) / threads;
    hipLaunchKernelGGL(qlayer_mps_kernel, dim3(blocks), dim3(threads), 0, stream,
                       x, w, out, half);
}